// Round 9
// baseline (222.755 us; speedup 1.0000x reference)
//
#include <hip/hip_runtime.h>
#include <hip/hip_bf16.h>

// SimCSE loss: loss = mean_i( logsumexp_j(sim[i][j]) - sim[i][i] ),
// sim = normalize(q) @ normalize(c)^T / 0.05.  N=8192, D=768, fp32 in, scalar out.
//
// Round-9: MX-fp8 GEMM. Inputs normalized+cast to OCP e4m3 (row-major, 768B/row).
// mfma_scale_f32_16x16x128_f8f6f4 with all scale bytes 0x7F (=1.0, identity) ->
// 2x MFMA rate vs bf16 AND half the LDS/staging bytes per unit K. 256x256 tile,
// 8 waves (2Mx4N), K-tile=128 elems (128B), 6 K-tiles, 128KiB LDS dbuf,
// 4-phase/K-tile counted-vmcnt schedule (round-8 skeleton re-derived).
// Swizzle: byte ^= (row&7)<<4 involution on 16B units (16-row frags -> 2-way free).
// diag in fp32 (exact); epilogue exp-rowsum unchanged.

#define NROWS 8192
#define DDIM  768
#define ROWB  768               // bytes per fp8 row
#define NKT   6                 // K-tiles of 128 elements
#define GRID_T (NROWS / 256)    // 32 tiles per dim

constexpr float INV_TEMP = 20.0f;   // 1/0.05
constexpr float NORM_EPS = 1e-8f;

typedef __attribute__((ext_vector_type(4))) float  f32x4;
typedef __attribute__((ext_vector_type(4))) int    i32x4;

// ---------------------------------------------------------------- fused normalize + diag
// One WAVE per row: read q_i,c_i once (fp32), write fp8 qn_i,cn_i + fp32 diag.
__global__ void norm_diag_kernel(const float* __restrict__ q, const float* __restrict__ c,
                                 char* __restrict__ qn, char* __restrict__ cn,
                                 float* __restrict__ diag) {
    const int row  = (blockIdx.x * 256 + threadIdx.x) >> 6;
    const int lane = threadIdx.x & 63;
    const float4* qv = (const float4*)(q + (size_t)row * DDIM);
    const float4* cv = (const float4*)(c + (size_t)row * DDIM);
    float4 a[3], b[3];
    #pragma unroll
    for (int j = 0; j < 3; ++j) { a[j] = qv[lane + j * 64]; b[j] = cv[lane + j * 64]; }
    float ssq = 0.f, ssc = 0.f, dot = 0.f;
    #pragma unroll
    for (int j = 0; j < 3; ++j) {
        ssq += a[j].x * a[j].x + a[j].y * a[j].y + a[j].z * a[j].z + a[j].w * a[j].w;
        ssc += b[j].x * b[j].x + b[j].y * b[j].y + b[j].z * b[j].z + b[j].w * b[j].w;
        dot += a[j].x * b[j].x + a[j].y * b[j].y + a[j].z * b[j].z + a[j].w * b[j].w;
    }
    #pragma unroll
    for (int m = 32; m; m >>= 1) {
        ssq += __shfl_xor(ssq, m);
        ssc += __shfl_xor(ssc, m);
        dot += __shfl_xor(dot, m);
    }
    float invq = 1.0f / fmaxf(sqrtf(ssq), NORM_EPS);
    float invc = 1.0f / fmaxf(sqrtf(ssc), NORM_EPS);
    if (lane == 0) diag[row] = dot * invq * invc * INV_TEMP;
    int* qo = (int*)(qn + (size_t)row * ROWB);
    int* co = (int*)(cn + (size_t)row * ROWB);
    #pragma unroll
    for (int j = 0; j < 3; ++j) {
        int wq = __builtin_amdgcn_cvt_pk_fp8_f32(a[j].x * invq, a[j].y * invq, 0, false);
        wq     = __builtin_amdgcn_cvt_pk_fp8_f32(a[j].z * invq, a[j].w * invq, wq, true);
        int wc = __builtin_amdgcn_cvt_pk_fp8_f32(b[j].x * invc, b[j].y * invc, 0, false);
        wc     = __builtin_amdgcn_cvt_pk_fp8_f32(b[j].z * invc, b[j].w * invc, wc, true);
        qo[lane + j * 64] = wq;
        co[lane + j * 64] = wc;
    }
}

// ---------------------------------------------------------------- GEMM + expsum
__device__ __forceinline__ void async16(void* l, const void* g) {
    __builtin_amdgcn_global_load_lds(
        (const __attribute__((address_space(1))) void*)g,
        (__attribute__((address_space(3))) void*)l, 16, 0, 0);
}

#define BARRIER __builtin_amdgcn_s_barrier()
#define SCHED0  __builtin_amdgcn_sched_barrier(0)
#define PRIO1   __builtin_amdgcn_s_setprio(1)
#define PRIO0   __builtin_amdgcn_s_setprio(0)
#define VMCNT(n) do { asm volatile("s_waitcnt vmcnt(" #n ")" ::: "memory"); } while (0)

// LDS map (bytes): parity p: A at p*65536 (32KB, [256 rows][128B]),
// B at 32768 + p*65536 (32KB, [256 cols][128B]).
// STAGE_*2 stages quarters Q and Q+1 (64 rows each, 2 instrs/thread).
#define STAGE_A2(P, Q, KT) do {                                             \
    const char* _g = aG + (size_t)(Q) * 64 * ROWB + (size_t)(KT) * 128;     \
    char* _l = lds + (P) * 65536 + (Q) * 8192 + dstW;                       \
    async16(_l, _g);                                                        \
    async16(_l + 8192, _g + 64 * ROWB);                                     \
} while (0)
#define STAGE_B2(P, Q, KT) do {                                             \
    const char* _g = bG + (size_t)(Q) * 64 * ROWB + (size_t)(KT) * 128;     \
    char* _l = lds + 32768 + (P) * 65536 + (Q) * 8192 + dstW;               \
    async16(_l, _g);                                                        \
    async16(_l + 8192, _g + 64 * ROWB);                                     \
} while (0)

// A frags for row-half MH: rows wr*128 + MH*64 + mi*16 + (lane&15); 32B/lane
#define READ_A(P, MH) do {                                                  \
    const char* _ab = lds + (P) * 65536 + aBaseT + (MH) * 8192;             \
    _Pragma("unroll") for (int mi = 0; mi < 4; ++mi) {                      \
        a[mi][0] = *(const i32x4*)(_ab + mi * 2048 + xk0);                  \
        a[mi][1] = *(const i32x4*)(_ab + mi * 2048 + xk1);                  \
    }                                                                       \
} while (0)
// B frags for col-half NH: cols wc*64 + NH*32 + ni*16 + (lane&15)
#define READ_B(P, NH) do {                                                  \
    const char* _bb = lds + 32768 + (P) * 65536 + bBaseT + (NH) * 4096;     \
    _Pragma("unroll") for (int ni = 0; ni < 2; ++ni) {                      \
        bfr[NH][ni][0] = *(const i32x4*)(_bb + ni * 2048 + xk0);            \
        bfr[NH][ni][1] = *(const i32x4*)(_bb + ni * 2048 + xk1);            \
    }                                                                       \
} while (0)

// 8 MFMA scale-f8f6f4 (fmt 0 = OCP e4m3): quadrant (MH,NH), K=128 in one inst.
// Scales 0x7F7F7F7F = e8m0 1.0 everywhere -> exact identity.
#define MFMA_Q(MH, NH)                                                        \
    _Pragma("unroll") for (int mi = 0; mi < 4; ++mi)                          \
    _Pragma("unroll") for (int ni = 0; ni < 2; ++ni)                          \
        acc[(MH)*4+mi][(NH)*2+ni] =                                           \
            __builtin_amdgcn_mfma_scale_f32_16x16x128_f8f6f4(                 \
                __builtin_shufflevector(a[mi][0], a[mi][1], 0,1,2,3,4,5,6,7), \
                __builtin_shufflevector(bfr[NH][ni][0], bfr[NH][ni][1],       \
                                        0,1,2,3,4,5,6,7),                     \
                acc[(MH)*4+mi][(NH)*2+ni], 0, 0, 0, 0x7F7F7F7F, 0, 0x7F7F7F7F);

__launch_bounds__(512, 2)
__global__ void simgemm_kernel(const char* __restrict__ A, const char* __restrict__ B,
                               float* __restrict__ partial) {
    __shared__ __attribute__((aligned(16))) char smem[131072];
    char* lds = smem;

    const int bid = blockIdx.x;
    const int tm = bid >> 5, tn = bid & 31;
    const int rowBase = tm * 256, colBase = tn * 256;
    const int tid = threadIdx.x;
    const int wid = tid >> 6, lane = tid & 63;
    const int wr = wid >> 2, wc = wid & 3;

    // staging source (pre-swizzled involution on 16B units within the 128B K-tile)
    const int sr  = tid >> 3;
    const int scb = ((tid & 7) * 16) ^ ((sr & 7) << 4);
    const char* aG = A + (size_t)(rowBase + sr) * ROWB + scb;
    const char* bG = B + (size_t)(colBase + sr) * ROWB + scb;
    const int dstW = wid * 1024;

    // read addressing: lane holds 32B at k-bytes (lane>>4)*32, row=16k+(lane&15)
    const int aBaseT = (wr * 128 + (lane & 15)) * 128;
    const int bBaseT = (wc * 64 + (lane & 15)) * 128;
    const int xk0    = ((lane >> 4) * 32) ^ ((lane & 7) << 4);
    const int xk1    = xk0 ^ 16;

    f32x4 acc[8][4] = {};
    i32x4 a[4][2];
    i32x4 bfr[2][2][2];

    // ---- prologue: stage tile0 fully (buf0) + tile1 A q0,q1 (buf1)
    STAGE_A2(0, 0, 0); STAGE_A2(0, 2, 0);
    STAGE_B2(0, 0, 0); STAGE_B2(0, 2, 0);
    STAGE_A2(1, 0, 1);
    VMCNT(2);          // tile0 landed; tile1.Aq01 (2 loads) in flight
    BARRIER; SCHED0;
    READ_A(0, 0); READ_B(0, 0);
    SCHED0;

    #pragma unroll 1
    for (int i = 0; i < NKT; ++i) {
        const int P = i & 1;
        const int t1 = i + 1, t2 = i + 2;
        // ph1: MFMA(0,0)[A0,B0]; stage t1.A q2,q3 (buf P^1, free) | read B1
        if (t1 < NKT) STAGE_A2(P ^ 1, 2, t1);
        PRIO1; MFMA_Q(0, 0); PRIO0;
        BARRIER; SCHED0;
        READ_B(P, 1); SCHED0;
        // ph2: MFMA(0,1)[A0,B1]; stage t1.B q0,q1 | read A1
        if (t1 < NKT) STAGE_B2(P ^ 1, 0, t1);
        PRIO1; MFMA_Q(0, 1); PRIO0;
        BARRIER; SCHED0;
        READ_A(P, 1); SCHED0;
        // ph3: MFMA(1,0)[A1,B0]; stage t1.B q2,q3
        if (t1 < NKT) STAGE_B2(P ^ 1, 2, t1);
        PRIO1; MFMA_Q(1, 0); PRIO0;
        BARRIER; SCHED0;
        // ph4: MFMA(1,1)[A1,B1]; stage t2.A q0,q1 (buf P A-region: last A read
        // consumed ph3, ph3-end barrier passed -> safe); vmcnt -> t1 landed
        if (t2 < NKT) STAGE_A2(P, 0, t2);
        PRIO1; MFMA_Q(1, 1); PRIO0;
        if (t2 < NKT) { VMCNT(2); } else { VMCNT(0); }
        BARRIER; SCHED0;
        if (t1 < NKT) { READ_A(P ^ 1, 0); READ_B(P ^ 1, 0); SCHED0; }
    }

    // ---- epilogue: rowsum of exp(20*acc - 20) over this tile's 256 cols
    // C/D layout (16x16 shape, dtype-independent): col=lane&15, row=(lane>>4)*4+r
    __syncthreads();                       // all loads drained (VMCNT(0) at i=NKT-2/NKT-1)
    float* red = (float*)smem;             // [256][4]
    #pragma unroll
    for (int m = 0; m < 8; ++m) {
        #pragma unroll
        for (int r = 0; r < 4; ++r) {
            float s = 0.f;
            #pragma unroll
            for (int n = 0; n < 4; ++n)
                s += __expf(fmaf(INV_TEMP, acc[m][n][r], -INV_TEMP));
            s += __shfl_xor(s, 1);
            s += __shfl_xor(s, 2);
            s += __shfl_xor(s, 4);
            s += __shfl_xor(s, 8);
            if ((lane & 15) == 0)
                red[(wr * 128 + m * 16 + (lane >> 4) * 4 + r) * 4 + wc] = s;
        }
    }
    __syncthreads();
    if (tid < 256)
        partial[(size_t)(rowBase + tid) * GRID_T + tn] =
            red[tid * 4 + 0] + red[tid * 4 + 1] + red[tid * 4 + 2] + red[tid * 4 + 3];
}

// ---------------------------------------------------------------- finalize
__global__ void finalize_kernel(const float* __restrict__ partial,
                                const float* __restrict__ diag,
                                float* __restrict__ out) {
    int row = blockIdx.x * 256 + threadIdx.x;
    const float4* p = (const float4*)(partial + (size_t)row * GRID_T);
    float z = 0.f;
    #pragma unroll
    for (int i = 0; i < GRID_T / 4; ++i) {
        float4 v = p[i];
        z += v.x + v.y + v.z + v.w;
    }
    float term = INV_TEMP + logf(z) - diag[row];
    #pragma unroll
    for (int m = 32; m; m >>= 1) term += __shfl_xor(term, m);
    __shared__ float wsum[4];
    if ((threadIdx.x & 63) == 0) wsum[threadIdx.x >> 6] = term;
    __syncthreads();
    if (threadIdx.x == 0) {
        float s = wsum[0] + wsum[1] + wsum[2] + wsum[3];
        atomicAdd(out, s * (1.0f / NROWS));
    }
}

// ---------------------------------------------------------------- launch
extern "C" void kernel_launch(void* const* d_in, const int* in_sizes, int n_in,
                              void* d_out, int out_size, void* d_ws, size_t ws_size,
                              hipStream_t stream) {
    const float* q = (const float*)d_in[0];
    const float* c = (const float*)d_in[1];
    float* out = (float*)d_out;

    char* ws = (char*)d_ws;
    char* qn = ws;                                               // 6.3 MB fp8
    char* cn = ws + (size_t)NROWS * ROWB;                        // 6.3 MB fp8
    float* diag = (float*)(ws + (size_t)2 * NROWS * ROWB);       // 32 KB
    float* partial = diag + NROWS;                               // 1 MB

    hipMemsetAsync(d_out, 0, sizeof(float), stream);

    norm_diag_kernel<<<NROWS / 4, 256, 0, stream>>>(q, c, qn, cn, diag);
    simgemm_kernel<<<GRID_T * GRID_T, 512, 0, stream>>>(qn, cn, partial);
    finalize_kernel<<<NROWS / 256, 256, 0, stream>>>(partial, diag, out);
}